// Round 7
// baseline (127.628 us; speedup 1.0000x reference)
//
#include <hip/hip_runtime.h>

#define BATCH  4096
#define LEN    8192
#define NB     12
#define TPB    256
#define EPT    32   // elements per thread; TPB*EPT == LEN

// shifted elu via polynomial: ep(a) = elu(a)+1.
// Weights prescaled so v = a*log2e/6 + 1  (u-domain: t = a*log2e in [-12,0]
// maps to u in [-1,1]). ep = max(P6(med3(v,-1,1)), 1 + a), where
// P6 approximates 2^{6(u-1)} on [-1,1] (Chebyshev, max err ~2.3e-3) and
// 1 + a = fma(v, 6ln2, 1-6ln2). All full-rate VALU, no transcendental.
__device__ __forceinline__ float ep_poly(float v) {
    const float C0 = 0.0152109f, C1 = 0.0764958f, C2 = 0.1480698f,
                C3 = 0.0993620f, C4 = 0.1326600f, C5 = 0.3221584f,
                C6 = 0.2037216f;
    const float SIXLN2   =  4.1588831f;   // 6*ln2
    const float ONEM6LN2 = -3.1588831f;   // 1 - 6*ln2
    float u = __builtin_amdgcn_fmed3f(v, -1.0f, 1.0f);
    float p = fmaf(C6, u, C5);
    p = fmaf(p, u, C4);
    p = fmaf(p, u, C3);
    p = fmaf(p, u, C2);
    p = fmaf(p, u, C1);
    p = fmaf(p, u, C0);
    float lin = fmaf(v, SIXLN2, ONEM6LN2);   // = 1 + a (exact)
    return fmaxf(p, lin);
}

__global__ __launch_bounds__(TPB, 8)
void resconv1d_kernel(const float* __restrict__ x_in,
                      const float* __restrict__ w1,
                      const float* __restrict__ b1,
                      const float* __restrict__ w2,
                      const float* __restrict__ b2,
                      float* __restrict__ out)
{
    // halo exchange buffers (double-buffered -> one barrier per block-iter)
    __shared__ float s_first[2][TPB];
    __shared__ float s_last [2][TPB];
    __shared__ float s_w[NB][6];   // {w10s6, w11s6, b1s6, aw20, aw21, cc}

    const int t   = threadIdx.x;
    const int row = blockIdx.x;

    // ---- load this thread's 32 contiguous elements (8x float4) ----
    const float* xp = x_in + (size_t)row * LEN + (size_t)t * EPT;
    float y[EPT];   // carried representation: y = x + D (D starts at 0)
    #pragma unroll
    for (int k = 0; k < EPT / 4; ++k) {
        float4 v = reinterpret_cast<const float4*>(xp)[k];
        y[4*k+0] = v.x; y[4*k+1] = v.y; y[4*k+2] = v.z; y[4*k+3] = v.w;
    }

    // ---- stage prescaled per-block weights in LDS once ----
    // L6 = log2e/6; v = w10s6*yl + w11s6*yc + b1s6 (+1 folded into b1s6)
    if (t < NB) {
        const float L6 = 0.2404491734814939f;   // log2(e)/6
        const float aw20 = 0.9f * w2[2*t];
        const float aw21 = 0.9f * w2[2*t+1];
        s_w[t][0] = w1[2*t]   * L6;               // w10s6
        s_w[t][1] = w1[2*t+1] * L6;               // w11s6
        s_w[t][2] = fmaf(b1[t], L6, 1.0f);        // b1s6 (D folded at use)
        s_w[t][3] = aw20;
        s_w[t][4] = aw21;
        s_w[t][5] = 0.9f * b2[t] - aw20 - aw21;   // cc
    }

    // loop-invariant halo indices / edge flags
    const int  idxl = (t > 0)       ? t - 1 : 0;
    const int  idxr = (t < TPB - 1) ? t + 1 : TPB - 1;
    const bool at_l = (t == 0);
    const bool at_r = (t == TPB - 1);

    float D = 0.0f;   // y = x + D; updated uniformly each iteration

    #pragma unroll 1
    for (int it = 0; it < NB; ++it) {
        const int buf = it & 1;
        s_first[buf][t] = y[0];
        s_last [buf][t] = y[EPT-1];
        __syncthreads();   // also covers the one-time s_w writes (it==0)

        const float w10s = s_w[it][0];
        const float w11s = s_w[it][1];
        const float b1sr = s_w[it][2];
        const float aw20 = s_w[it][3];
        const float aw21 = s_w[it][4];
        const float cc   = s_w[it][5];

        // fold the carried offset into the conv1 bias:
        // v = w10s*y_l + w11s*y_c + (b1*L6 + 1 - D*(w10s+w11s))
        const float b1p = fmaf(-D, w10s + w11s, b1sr);

        // halo in y-representation; row edge x==0 corresponds to y==D
        const float yl = at_l ? D : s_last [buf][idxl];
        const float yr = at_r ? D : s_first[buf][idxr];

        float v0  = fmaf(w10s, yl, fmaf(w11s, y[0], b1p));
        float ep0 = ep_poly(v0);
        #pragma unroll
        for (int j = 0; j < EPT; ++j) {
            const float yn  = (j < EPT - 1) ? y[j+1] : yr;   // static select
            const float v1  = fmaf(w10s, y[j], fmaf(w11s, yn, b1p));
            const float ep1 = ep_poly(v1);
            // x_new = x + cc + aw20*ep0 + aw21*ep1   (offset carried in D)
            y[j] = fmaf(aw20, ep0, fmaf(aw21, ep1, y[j]));
            ep0 = ep1;
        }
        D -= cc;   // uniform across all threads
        // next iteration writes the other halo buffer; one barrier/iter safe
    }

    // ---- store: undo the carried offset (x = y - D_final) ----
    float* op = out + (size_t)row * LEN + (size_t)t * EPT;
    #pragma unroll
    for (int k = 0; k < EPT / 4; ++k) {
        float4 v = make_float4(y[4*k+0] - D, y[4*k+1] - D,
                               y[4*k+2] - D, y[4*k+3] - D);
        reinterpret_cast<float4*>(op)[k] = v;
    }
}

extern "C" void kernel_launch(void* const* d_in, const int* in_sizes, int n_in,
                              void* d_out, int out_size, void* d_ws, size_t ws_size,
                              hipStream_t stream) {
    const float* x  = (const float*)d_in[0];
    const float* w1 = (const float*)d_in[1];
    const float* b1 = (const float*)d_in[2];
    const float* w2 = (const float*)d_in[3];
    const float* b2 = (const float*)d_in[4];
    float* out = (float*)d_out;

    resconv1d_kernel<<<dim3(BATCH), dim3(TPB), 0, stream>>>(x, w1, b1, w2, b2, out);
}

// Round 8
// 100.621 us; speedup vs baseline: 1.2684x; 1.2684x over previous
//
#include <hip/hip_runtime.h>

#define BATCH  4096
#define LEN    8192
#define NB     12
#define TPB    256
#define EPT    32   // elements per thread; TPB*EPT == LEN

// shifted elu: ep(a) = elu(a)+1, input as = a*log2e (weights prescaled).
// ep = max(clamp01(exp2(as)), 1 + ln2*as)
//   clamp01(exp2(as)) == exp2(min(as,0)) for ALL as (monotone; +inf->1, 0->0)
//   expressed as fmed3(e,0,1): single op, foldable into v_exp's clamp bit.
__device__ __forceinline__ float ep_f(float as) {
    const float LN2 = 0.6931471805599453f;
    float e = __builtin_amdgcn_exp2f(as);
    e = __builtin_amdgcn_fmed3f(e, 0.0f, 1.0f);   // clamp-to-[0,1] idiom
    return fmaxf(e, fmaf(as, LN2, 1.0f));
}

__global__ __launch_bounds__(TPB, 8)
void resconv1d_kernel(const float* __restrict__ x_in,
                      const float* __restrict__ w1,
                      const float* __restrict__ b1,
                      const float* __restrict__ w2,
                      const float* __restrict__ b2,
                      float* __restrict__ out)
{
    // halo exchange buffers (double-buffered -> one barrier per block-iter)
    __shared__ float s_first[2][TPB];
    __shared__ float s_last [2][TPB];

    const int t   = threadIdx.x;
    const int row = blockIdx.x;

    // ---- load this thread's 32 contiguous elements (8x float4) ----
    const float* xp = x_in + (size_t)row * LEN + (size_t)t * EPT;
    float y[EPT];   // carried representation: y = x + D (D starts at 0)
    #pragma unroll
    for (int k = 0; k < EPT / 4; ++k) {
        float4 v = reinterpret_cast<const float4*>(xp)[k];
        y[4*k+0] = v.x; y[4*k+1] = v.y; y[4*k+2] = v.z; y[4*k+3] = v.w;
    }

    // loop-invariant halo indices / edge flags
    const int  idxl = (t > 0)       ? t - 1 : 0;
    const int  idxr = (t < TPB - 1) ? t + 1 : TPB - 1;
    const bool at_l = (t == 0);
    const bool at_r = (t == TPB - 1);

    float D = 0.0f;   // y = x + D; updated uniformly each iteration

    #pragma unroll 1
    for (int it = 0; it < NB; ++it) {
        const int buf = it & 1;
        s_first[buf][t] = y[0];
        s_last [buf][t] = y[EPT-1];
        __syncthreads();

        // ---- uniform weight loads (it is loop-uniform -> s_load/SGPR) ----
        const float LOG2E = 1.4426950408889634f;
        const float w10s = w1[2*it]   * LOG2E;
        const float w11s = w1[2*it+1] * LOG2E;
        const float aw20 = 0.9f * w2[2*it];
        const float aw21 = 0.9f * w2[2*it+1];
        const float cc   = 0.9f * b2[it] - aw20 - aw21;
        // fold the carried offset into the conv1 bias:
        // as = w10s*y_l + w11s*y_c + (b1*log2e - D*(w10s+w11s))
        const float b1p  = fmaf(-D, w10s + w11s, b1[it] * LOG2E);

        // halo in y-representation; row edge x==0 corresponds to y==D
        const float yl = at_l ? D : s_last [buf][idxl];
        const float yr = at_r ? D : s_first[buf][idxr];

        float as0 = fmaf(w10s, yl, fmaf(w11s, y[0], b1p));
        float ep0 = ep_f(as0);
        #pragma unroll
        for (int j = 0; j < EPT; ++j) {
            const float yn  = (j < EPT - 1) ? y[j+1] : yr;   // static select
            const float as1 = fmaf(w10s, y[j], fmaf(w11s, yn, b1p));
            const float ep1 = ep_f(as1);
            // x_new = x + cc + aw20*ep0 + aw21*ep1   (offset carried in D)
            y[j] = fmaf(aw20, ep0, fmaf(aw21, ep1, y[j]));
            ep0 = ep1;
        }
        D -= cc;   // uniform across all threads
        // next iteration writes the other halo buffer; one barrier/iter safe
    }

    // ---- store: undo the carried offset (x = y - D_final) ----
    float* op = out + (size_t)row * LEN + (size_t)t * EPT;
    #pragma unroll
    for (int k = 0; k < EPT / 4; ++k) {
        float4 v = make_float4(y[4*k+0] - D, y[4*k+1] - D,
                               y[4*k+2] - D, y[4*k+3] - D);
        reinterpret_cast<float4*>(op)[k] = v;
    }
}

extern "C" void kernel_launch(void* const* d_in, const int* in_sizes, int n_in,
                              void* d_out, int out_size, void* d_ws, size_t ws_size,
                              hipStream_t stream) {
    const float* x  = (const float*)d_in[0];
    const float* w1 = (const float*)d_in[1];
    const float* b1 = (const float*)d_in[2];
    const float* w2 = (const float*)d_in[3];
    const float* b2 = (const float*)d_in[4];
    float* out = (float*)d_out;

    resconv1d_kernel<<<dim3(BATCH), dim3(TPB), 0, stream>>>(x, w1, b1, w2, b2, out);
}